// Round 7
// baseline (280.996 us; speedup 1.0000x reference)
//
#include <hip/hip_runtime.h>
#include <math.h>

#define S_LEN 4096
#define DMODEL 2048
#define NH 16
#define NKVH 4
#define HD 128
#define LDQKV 3072   // NH*HD + 2*NKVH*HD

typedef __attribute__((ext_vector_type(4))) float f32x4;
typedef __attribute__((ext_vector_type(8))) short bf16x8;
typedef __attribute__((ext_vector_type(4))) unsigned short us4;

static __device__ __forceinline__ unsigned short f2bf(float f) {
  unsigned int u = __builtin_bit_cast(unsigned int, f);
  u += 0x7fffu + ((u >> 16) & 1u);
  return (unsigned short)(u >> 16);
}
static __device__ __forceinline__ float bf2f(unsigned short h) {
  unsigned int u = ((unsigned int)h) << 16;
  return __builtin_bit_cast(float, u);
}
static __device__ __forceinline__ unsigned int cvt_pk_bf16(float lo, float hi) {
  unsigned int r;
  asm("v_cvt_pk_bf16_f32 %0, %1, %2" : "=v"(r) : "v"(lo), "v"(hi));
  return r;
}

#define GLDS16(g, l) __builtin_amdgcn_global_load_lds( \
    (__attribute__((address_space(1))) void*)(g), \
    (__attribute__((address_space(3))) void*)(l), 16, 0, 0)

// ---------------- prep kernels ----------------

__global__ __launch_bounds__(256) void k_cast_bf16(const float* __restrict__ src,
                                                   unsigned short* __restrict__ dst, int n4) {
  int i = blockIdx.x * 256 + threadIdx.x;
  if (i >= n4) return;
  const float4* s = (const float4*)src;
  float4 v = s[i];
  us4 o = { f2bf(v.x), f2bf(v.y), f2bf(v.z), f2bf(v.w) };
  *(us4*)(dst + (size_t)i * 4) = o;
}

// dst[n*K+k] = bf16(src[k*N+n]); K,N multiples of 64
__global__ __launch_bounds__(256) void k_transpose_bf16(const float* __restrict__ src,
    unsigned short* __restrict__ dst, int K, int N) {
  __shared__ float tile[64][65];
  int k0 = blockIdx.x * 64, n0 = blockIdx.y * 64;
  int t = threadIdx.x;
#pragma unroll
  for (int i = 0; i < 16; ++i) {
    int idx = t + i * 256;
    int r = idx >> 6, c = idx & 63;
    tile[r][c] = src[(size_t)(k0 + r) * N + n0 + c];
  }
  __syncthreads();
#pragma unroll
  for (int i = 0; i < 16; ++i) {
    int idx = t + i * 256;
    int r = idx >> 6, c = idx & 63;
    dst[(size_t)(n0 + r) * K + k0 + c] = f2bf(tile[c][r]);
  }
}

// in-place RoPE on Q (cols 0..2047) and K (cols 2048..2559) of QKV [S][3072]
// Q additionally scaled by log2(e)/sqrt(HD). Uses cos[d+64]==cos[d].
__global__ __launch_bounds__(256) void k_rope(unsigned short* __restrict__ QKV,
    const float* __restrict__ cp, const float* __restrict__ sp) {
  int gid = blockIdx.x * 256 + threadIdx.x;   // S*20*16 total
  int d4 = (gid & 15) * 4;
  int hh = (gid >> 4) % 20;
  int s = gid / 320;
  int col = hh < NH ? hh * HD : DMODEL + (hh - NH) * HD;
  float qs = hh < NH ? 0.12751589341664477f : 1.0f;  // log2e/sqrt(128) for Q heads
  size_t base = (size_t)s * LDQKV + col + d4;
  us4 x1 = *(us4*)(QKV + base);
  us4 x2 = *(us4*)(QKV + base + 64);
  float4 c = *(const float4*)(cp + s * HD + d4);
  float4 sn = *(const float4*)(sp + s * HD + d4);
  us4 o1, o2;
  o1[0] = f2bf((bf2f(x1[0]) * c.x - bf2f(x2[0]) * sn.x) * qs);
  o1[1] = f2bf((bf2f(x1[1]) * c.y - bf2f(x2[1]) * sn.y) * qs);
  o1[2] = f2bf((bf2f(x1[2]) * c.z - bf2f(x2[2]) * sn.z) * qs);
  o1[3] = f2bf((bf2f(x1[3]) * c.w - bf2f(x2[3]) * sn.w) * qs);
  o2[0] = f2bf((bf2f(x2[0]) * c.x + bf2f(x1[0]) * sn.x) * qs);
  o2[1] = f2bf((bf2f(x2[1]) * c.y + bf2f(x1[1]) * sn.y) * qs);
  o2[2] = f2bf((bf2f(x2[2]) * c.z + bf2f(x1[2]) * sn.z) * qs);
  o2[3] = f2bf((bf2f(x2[3]) * c.w + bf2f(x1[3]) * sn.w) * qs);
  *(us4*)(QKV + base) = o1;
  *(us4*)(QKV + base + 64) = o2;
}

// Vt[(kvh*128+d)*S + blk*64 + c] = QKV[blk*64 + pi(c)][2560 + kvh*128 + d]
// pi(c) = (c&3)*16 + (c>>2)  — k-permutation matching the P storage layout.
__global__ __launch_bounds__(256) void k_transpose_v(const unsigned short* __restrict__ QKV,
    unsigned short* __restrict__ Vt) {
  __shared__ unsigned short tile[64][72];
  int s0 = blockIdx.x * 64, c0 = blockIdx.y * 64;
  int t = threadIdx.x;
#pragma unroll
  for (int i = 0; i < 16; ++i) {
    int idx = t + i * 256;
    int r = idx >> 6, c = idx & 63;
    tile[r][c] = QKV[(size_t)(s0 + r) * LDQKV + DMODEL + NKVH * HD + c0 + c];
  }
  __syncthreads();
#pragma unroll
  for (int i = 0; i < 16; ++i) {
    int idx = t + i * 256;
    int r = idx >> 6, c = idx & 63;
    int pc = (c & 3) * 16 + (c >> 2);
    Vt[(size_t)(c0 + r) * S_LEN + s0 + c] = tile[pc][r];
  }
}

// ---------------- 8-phase GEMM: C[M][N] = A[M][K] * Bt[N][K]^T ----------------
// BM=256, BN=128, BK=64, 8 waves (4M x 2N, 64x64 each), triple-buffered LDS,
// counted vmcnt (T3/T4), setprio around MFMA (T5), XCD-bijective block swizzle.

#define MFMA16(a, b, c) __builtin_amdgcn_mfma_f32_16x16x32_bf16(a, b, c, 0, 0, 0)

// One K-tile: 4 phases {reads | stage-unit | barrier | 8 MFMA | barrier}.
template<bool DO_STAGE, int VM>
__device__ __forceinline__ void gemm_ktile(
    const unsigned short* __restrict__ Ac, const unsigned short* __restrict__ Bc,
    const unsigned short* __restrict__ Ag, const unsigned short* __restrict__ Bg,
    char* Astg, char* Bstg, int K,
    f32x4 (&acc)[4][4], int lr, int lg, int wr, int wc, int wave, int srow, int gsel) {
  bf16x8 aq[2][2], b0q[2][2], b1q[2][2];
  const int gbase = ((lg) ^ (lr & 7));  // granule for ks=0; ks=1 adds 4 (XOR with row&7<8 keeps 4-bit separable)
  (void)gbase;
  // ---- P1: read A(mq0) + B(nq0); stage A-half0 of tile t+2 ----
#pragma unroll
  for (int f = 0; f < 2; ++f) {
    const int ra = wr + f * 16 + lr;
    const int rb = wc + f * 16 + lr;
#pragma unroll
    for (int ks = 0; ks < 2; ++ks) {
      aq[f][ks]  = *(const bf16x8*)(Ac + ra * 64 + (((ks * 4 + lg) ^ (lr & 7)) * 8));
      b0q[f][ks] = *(const bf16x8*)(Bc + rb * 64 + (((ks * 4 + lg) ^ (lr & 7)) * 8));
    }
  }
  if (DO_STAGE) {
#pragma unroll
    for (int j = 0; j < 2; ++j) {
      const int row = j * 64 + srow;
      GLDS16(Ag + (size_t)row * K + ((gsel ^ (row & 7)) * 8), Astg + (j * 8192 + wave * 1024));
    }
  }
  __builtin_amdgcn_s_barrier();
  __builtin_amdgcn_s_setprio(1);
#pragma unroll
  for (int mf = 0; mf < 2; ++mf)
#pragma unroll
    for (int nf = 0; nf < 2; ++nf)
#pragma unroll
      for (int ks = 0; ks < 2; ++ks)
        acc[mf][nf] = MFMA16(aq[mf][ks], b0q[nf][ks], acc[mf][nf]);
  __builtin_amdgcn_s_setprio(0);
  __builtin_amdgcn_s_barrier();
  // ---- P2: read B(nq1); stage A-half1 ----
#pragma unroll
  for (int f = 0; f < 2; ++f) {
    const int rb = wc + 32 + f * 16 + lr;
#pragma unroll
    for (int ks = 0; ks < 2; ++ks)
      b1q[f][ks] = *(const bf16x8*)(Bc + rb * 64 + (((ks * 4 + lg) ^ (lr & 7)) * 8));
  }
  if (DO_STAGE) {
#pragma unroll
    for (int j = 0; j < 2; ++j) {
      const int row = 128 + j * 64 + srow;
      GLDS16(Ag + (size_t)row * K + ((gsel ^ (row & 7)) * 8), Astg + (16384 + j * 8192 + wave * 1024));
    }
  }
  __builtin_amdgcn_s_barrier();
  __builtin_amdgcn_s_setprio(1);
#pragma unroll
  for (int mf = 0; mf < 2; ++mf)
#pragma unroll
    for (int nf = 0; nf < 2; ++nf)
#pragma unroll
      for (int ks = 0; ks < 2; ++ks)
        acc[mf][2 + nf] = MFMA16(aq[mf][ks], b1q[nf][ks], acc[mf][2 + nf]);
  __builtin_amdgcn_s_setprio(0);
  __builtin_amdgcn_s_barrier();
  // ---- P3: read A(mq1) (overwrite aq); stage B ----
#pragma unroll
  for (int f = 0; f < 2; ++f) {
    const int ra = wr + 32 + f * 16 + lr;
#pragma unroll
    for (int ks = 0; ks < 2; ++ks)
      aq[f][ks] = *(const bf16x8*)(Ac + ra * 64 + (((ks * 4 + lg) ^ (lr & 7)) * 8));
  }
  if (DO_STAGE) {
#pragma unroll
    for (int j = 0; j < 2; ++j) {
      const int row = j * 64 + srow;
      GLDS16(Bg + (size_t)row * K + ((gsel ^ (row & 7)) * 8), Bstg + (j * 8192 + wave * 1024));
    }
  }
  __builtin_amdgcn_s_barrier();
  __builtin_amdgcn_s_setprio(1);
#pragma unroll
  for (int mf = 0; mf < 2; ++mf)
#pragma unroll
    for (int nf = 0; nf < 2; ++nf)
#pragma unroll
      for (int ks = 0; ks < 2; ++ks)
        acc[2 + mf][2 + nf] = MFMA16(aq[mf][ks], b1q[nf][ks], acc[2 + mf][2 + nf]);
  __builtin_amdgcn_s_setprio(0);
  __builtin_amdgcn_s_barrier();
  // ---- P4: no reads/stages; MFMA q(1,0); counted vmcnt; barrier ----
  __builtin_amdgcn_s_setprio(1);
#pragma unroll
  for (int mf = 0; mf < 2; ++mf)
#pragma unroll
    for (int nf = 0; nf < 2; ++nf)
#pragma unroll
      for (int ks = 0; ks < 2; ++ks)
        acc[2 + mf][nf] = MFMA16(aq[mf][ks], b0q[nf][ks], acc[2 + mf][nf]);
  __builtin_amdgcn_s_setprio(0);
  if (VM == 6)      asm volatile("s_waitcnt vmcnt(6)" ::: "memory");
  else if (VM == 0) asm volatile("s_waitcnt vmcnt(0)" ::: "memory");
  __builtin_amdgcn_s_barrier();
}

template<int OUTF32>
__global__ __launch_bounds__(512, 1) void k_gemm8(
    const unsigned short* __restrict__ A, const unsigned short* __restrict__ Bt,
    void* __restrict__ Cp, int M, int N, int K, int nbm, int nbn) {
  __shared__ __attribute__((aligned(16))) unsigned short Ab[3][256 * 64];
  __shared__ __attribute__((aligned(16))) unsigned short Bb[3][128 * 64];
  const int t = threadIdx.x, wave = t >> 6, lane = t & 63;
  const int lr = lane & 15, lg = lane >> 4;
  const int srow = wave * 8 + (lane >> 3);
  const int gsel = lane & 7;
  // XCD-bijective swizzle (gridDim.x % 8 == 0 for both calls), m-major chunks
  const int nwg = nbm * nbn;
  const int q8 = nwg >> 3;
  const int wg = (blockIdx.x & 7) * q8 + (blockIdx.x >> 3);
  const int bm = (wg % nbm) * 256, bn = (wg / nbm) * 128;
  const int wr = (wave >> 1) * 64, wc = (wave & 1) * 64;

  f32x4 acc[4][4];
#pragma unroll
  for (int i = 0; i < 4; ++i)
#pragma unroll
    for (int j = 0; j < 4; ++j) acc[i][j] = (f32x4){0.f, 0.f, 0.f, 0.f};

  // prologue: stage K-tiles 0 and 1
#pragma unroll
  for (int tt = 0; tt < 2; ++tt) {
#pragma unroll
    for (int u = 0; u < 2; ++u)
#pragma unroll
      for (int j = 0; j < 2; ++j) {
        const int row = u * 128 + j * 64 + srow;
        GLDS16(A + (size_t)(bm + row) * K + tt * 64 + ((gsel ^ (row & 7)) * 8),
               (char*)Ab[tt] + u * 16384 + j * 8192 + wave * 1024);
      }
#pragma unroll
    for (int j = 0; j < 2; ++j) {
      const int row = j * 64 + srow;
      GLDS16(Bt + (size_t)(bn + row) * K + tt * 64 + ((gsel ^ (row & 7)) * 8),
             (char*)Bb[tt] + j * 8192 + wave * 1024);
    }
  }
  asm volatile("s_waitcnt vmcnt(6)" ::: "memory");   // tile0 landed
  __builtin_amdgcn_s_barrier();

  const unsigned short *a0 = Ab[0], *a1 = Ab[1], *a2 = Ab[2];
  const unsigned short *b0 = Bb[0], *b1 = Bb[1], *b2 = Bb[2];
  const int nkt = K >> 6;
  for (int kt = 0; kt < nkt - 2; ++kt) {
    gemm_ktile<true, 6>(a0, b0,
        A + (size_t)bm * K + (kt + 2) * 64, Bt + (size_t)bn * K + (kt + 2) * 64,
        (char*)a2, (char*)b2, K, acc, lr, lg, wr, wc, wave, srow, gsel);
    const unsigned short* ta = a0; a0 = a1; a1 = a2; a2 = ta;
    const unsigned short* tb = b0; b0 = b1; b1 = b2; b2 = tb;
  }
  gemm_ktile<false, 0>(a0, b0, A, Bt, (char*)a2, (char*)b2, K, acc, lr, lg, wr, wc, wave, srow, gsel);
  {
    const unsigned short* ta = a0; a0 = a1; a1 = a2; a2 = ta;
    const unsigned short* tb = b0; b0 = b1; b1 = b2; b2 = tb;
  }
  gemm_ktile<false, -1>(a0, b0, A, Bt, (char*)a2, (char*)b2, K, acc, lr, lg, wr, wc, wave, srow, gsel);

  // epilogue
#pragma unroll
  for (int mi = 0; mi < 4; ++mi)
#pragma unroll
    for (int ni = 0; ni < 4; ++ni)
#pragma unroll
      for (int r = 0; r < 4; ++r) {
        const int m = bm + wr + mi * 16 + lg * 4 + r;
        const int n = bn + wc + ni * 16 + lr;
        if (OUTF32) ((float*)Cp)[(size_t)m * N + n] = acc[mi][ni][r];
        else ((unsigned short*)Cp)[(size_t)m * N + n] = f2bf(acc[mi][ni][r]);
      }
}

// ---------------- fused causal gated attention (v6: 8-wave, KVBLK=128) ----------------

#define STAGE_KV(kt_, buf_) do { \
  const int kv0_ = (kt_) * 128; \
  _Pragma("unroll") \
  for (int i_ = 0; i_ < 4; ++i_) { \
    const int cb_ = (wave * 4 + i_) * 64; \
    const int c_ = cb_ + lane; \
    const int row_ = c_ >> 4, kc_ = c_ & 15; \
    const int sw_ = (kc_ ^ (row_ & 7)) * 8; \
    GLDS16(Kp + (size_t)(kv0_ + row_) * LDQKV + sw_, (char*)Ks[buf_] + cb_ * 16); \
    GLDS16(Vp + (size_t)row_ * S_LEN + kv0_ + sw_, (char*)Vs[buf_] + cb_ * 16); \
  } \
} while (0)

__device__ __forceinline__ void qkt_one(const unsigned short* Kb,
    const bf16x8* qf, f32x4* sc, int lr, int lg) {
  __builtin_amdgcn_s_setprio(1);
#pragma unroll
  for (int cf = 0; cf < 8; ++cf) {
    sc[cf] = (f32x4){0.f, 0.f, 0.f, 0.f};
    const int row = cf * 16 + lr;
#pragma unroll
    for (int ks = 0; ks < 4; ++ks) {
      bf16x8 kb = *(const bf16x8*)(Kb + row * 128 + (((ks * 4 + lg) ^ (lr & 7)) * 8));
      sc[cf] = __builtin_amdgcn_mfma_f32_16x16x32_bf16(qf[ks], kb, sc[cf], 0, 0, 0);
    }
  }
  __builtin_amdgcn_s_setprio(0);
}

template<bool DIAG>
__device__ __forceinline__ void softmax_pv(
    f32x4* sc, const unsigned short* Vb, unsigned short (*PsW)[72],
    const float* g8, int kv0, int qbase,
    f32x4* acc, f32x4& acc_s, float* mrow, int lr, int lg,
    const bf16x8 vb_ones) {
  if (DIAG) {
#pragma unroll
    for (int cf = 0; cf < 8; ++cf) {
      const int kpos = kv0 + cf * 16 + lr;
#pragma unroll
      for (int r = 0; r < 4; ++r)
        sc[cf][r] = (kpos <= qbase + r) ? sc[cf][r] : -3e38f;
    }
  }
  float lmax[4];
#pragma unroll
  for (int r = 0; r < 4; ++r) {
    float a = fmaxf(fmaxf(sc[0][r], sc[1][r]), fmaxf(sc[2][r], sc[3][r]));
    float b = fmaxf(fmaxf(sc[4][r], sc[5][r]), fmaxf(sc[6][r], sc[7][r]));
    lmax[r] = fmaxf(a, b);
  }
  bool need = (lmax[0] > mrow[0] + 11.5416f) | (lmax[1] > mrow[1] + 11.5416f) |
              (lmax[2] > mrow[2] + 11.5416f) | (lmax[3] > mrow[3] + 11.5416f);
  if (__any(need)) {
    float tm[4] = {lmax[0], lmax[1], lmax[2], lmax[3]};
#pragma unroll
    for (int off = 8; off; off >>= 1)
#pragma unroll
      for (int r = 0; r < 4; ++r) tm[r] = fmaxf(tm[r], __shfl_xor(tm[r], off));
#pragma unroll
    for (int r = 0; r < 4; ++r) {
      const float mn = fmaxf(mrow[r], tm[r]);
      const float alpha = __builtin_amdgcn_exp2f(mrow[r] - mn);
      mrow[r] = mn;
#pragma unroll
      for (int j = 0; j < 8; ++j) acc[j][r] *= alpha;
      acc_s[r] *= alpha;
    }
  }
  // two 64-col halves: exp+pack+write P, then PV for that half.
#pragma unroll
  for (int hh = 0; hh < 2; ++hh) {
    const f32x4* s4 = sc + hh * 4;
    const float* g4 = g8 + hh * 4;
#pragma unroll
    for (int r = 0; r < 4; ++r) {
      float p0 = __builtin_amdgcn_exp2f(s4[0][r] - mrow[r]) * g4[0];
      float p1 = __builtin_amdgcn_exp2f(s4[1][r] - mrow[r]) * g4[1];
      float p2 = __builtin_amdgcn_exp2f(s4[2][r] - mrow[r]) * g4[2];
      float p3 = __builtin_amdgcn_exp2f(s4[3][r] - mrow[r]) * g4[3];
      uint2 pk = { cvt_pk_bf16(p0, p1), cvt_pk_bf16(p2, p3) };
      *(uint2*)(&PsW[lg * 4 + r][lr * 4]) = pk;
    }
    asm volatile("s_waitcnt lgkmcnt(0)" ::: "memory");
    __builtin_amdgcn_sched_barrier(0);
    __builtin_amdgcn_s_setprio(1);
#pragma unroll
    for (int ks = 0; ks < 2; ++ks) {
      bf16x8 pa = *(const bf16x8*)(&PsW[lr][ks * 32 + lg * 8]);
#pragma unroll
      for (int j = 0; j < 8; ++j) {
        const int d = j * 16 + lr;
        bf16x8 vb = *(const bf16x8*)(Vb + d * 128 + ((hh * 8 + ((ks * 4 + lg) ^ (lr & 7))) * 8));
        acc[j] = __builtin_amdgcn_mfma_f32_16x16x32_bf16(pa, vb, acc[j], 0, 0, 0);
      }
      acc_s = __builtin_amdgcn_mfma_f32_16x16x32_bf16(pa, vb_ones, acc_s, 0, 0, 0);
    }
    __builtin_amdgcn_s_setprio(0);
  }
}

__global__ __launch_bounds__(512) void k_attn(
    const unsigned short* __restrict__ QKV, const unsigned short* __restrict__ Vt,
    const float* __restrict__ gate, unsigned short* __restrict__ Oattn) {
  __shared__ __attribute__((aligned(16))) unsigned short Ks[2][128 * 128];
  __shared__ __attribute__((aligned(16))) unsigned short Vs[2][128 * 128];
  __shared__ __attribute__((aligned(16))) unsigned short Ps[8][16][72];
  const int h = blockIdx.y, kvh = h >> 2;
  const int bx = blockIdx.x;           // 0..15
  const int t = threadIdx.x, wave = t >> 6, lane = t & 63;
  const int lr = lane & 15, lg = lane >> 4;
  const unsigned short* Qp = QKV + h * HD;
  const unsigned short* Kp = QKV + DMODEL + kvh * HD;
  const unsigned short* Vp = Vt + (size_t)kvh * HD * S_LEN;
  unsigned short (*PsW)[72] = Ps[wave];
  bf16x8 vb_ones;
  {
    const short one = (short)0x3F80, z = 0;
    const short e = (lr == 0) ? one : z;
    vb_ones = (bf16x8){e, e, e, e, e, e, e, e};
  }

  for (int half = 0; half < 2; ++half) {
    const int st = half ? bx : (31 - bx);   // super-tile (128 rows), heavy first
    const int q0 = st * 128;
    const int nt = st + 1;                  // KV tiles (128 wide) 0..nt-1
    const int qbase = q0 + wave * 16 + lg * 4;

    bf16x8 qf[4];
    {
      const size_t qoff = (size_t)(q0 + wave * 16 + lr) * LDQKV;
#pragma unroll
      for (int ks = 0; ks < 4; ++ks)
        qf[ks] = *(const bf16x8*)(Qp + qoff + ks * 32 + lg * 8);
    }
    f32x4 acc[8];
#pragma unroll
    for (int j = 0; j < 8; ++j) acc[j] = (f32x4){0.f, 0.f, 0.f, 0.f};
    f32x4 acc_s = (f32x4){0.f, 0.f, 0.f, 0.f};
    float mrow[4] = {-3e38f, -3e38f, -3e38f, -3e38f};
    f32x4 sc[8];
    float g8[8];

    __builtin_amdgcn_s_barrier();        // protect buf0 from previous half's reads
    STAGE_KV(0, 0);

    int kt = 0;
    for (; kt < nt - 1; ++kt) {
      STAGE_KV(kt + 1, (kt + 1) & 1);
      asm volatile("s_waitcnt vmcnt(8)" ::: "memory");
      __builtin_amdgcn_s_barrier();
#pragma unroll
      for (int cf = 0; cf < 8; ++cf) g8[cf] = gate[kt * 128 + cf * 16 + lr];
      qkt_one(Ks[kt & 1], qf, sc, lr, lg);
      softmax_pv<false>(sc, Vs[kt & 1], PsW, g8, kt * 128, qbase, acc, acc_s, mrow, lr, lg, vb_ones);
      __builtin_amdgcn_s_barrier();
    }
    // diagonal tile (kv0 == q0)
    {
      asm volatile("s_waitcnt vmcnt(0)" ::: "memory");
      __builtin_amdgcn_s_barrier();
#pragma unroll
      for (int cf = 0; cf < 8; ++cf) g8[cf] = gate[kt * 128 + cf * 16 + lr];
      qkt_one(Ks[kt & 1], qf, sc, lr, lg);
      softmax_pv<true>(sc, Vs[kt & 1], PsW, g8, kt * 128, qbase, acc, acc_s, mrow, lr, lg, vb_ones);
    }

    float inv[4];
#pragma unroll
    for (int r = 0; r < 4; ++r)
      inv[r] = 1.0f / __shfl(acc_s[r], lane & 48);
#pragma unroll
    for (int j = 0; j < 8; ++j)
#pragma unroll
      for (int r = 0; r < 4; ++r)
        Oattn[(size_t)(qbase + r) * DMODEL + h * HD + j * 16 + lr] = f2bf(acc[j][r] * inv[r]);
  }
}

// ---------------- launch ----------------

extern "C" void kernel_launch(void* const* d_in, const int* in_sizes, int n_in,
                              void* d_out, int out_size, void* d_ws, size_t ws_size,
                              hipStream_t stream) {
  (void)in_sizes; (void)n_in; (void)out_size; (void)ws_size;
  const float* hid  = (const float*)d_in[0];
  // d_in[1] = attention_mask (pure causal; recomputed inline, never read)
  const float* cosp = (const float*)d_in[2];
  const float* sinp = (const float*)d_in[3];
  const float* gate = (const float*)d_in[4];
  const float* Wq   = (const float*)d_in[5];
  const float* Wk   = (const float*)d_in[6];
  const float* Wv   = (const float*)d_in[7];
  const float* Wo   = (const float*)d_in[8];
  float* out = (float*)d_out;
  char* ws = (char*)d_ws;
  unsigned short* Xb   = (unsigned short*)(ws);                       // 16 MB  [4096][2048] bf16
  unsigned short* Wt   = (unsigned short*)(ws + (size_t)16777216);    // 12 MB  [3072][2048] bf16 (Wq|Wk|Wv)^T
  unsigned short* Wot  = (unsigned short*)(ws + (size_t)29360128);    //  8 MB  [2048][2048] bf16 Wo^T
  unsigned short* QKV  = (unsigned short*)(ws + (size_t)37748736);    // 24 MB  [4096][3072] bf16
  unsigned short* Oatt = (unsigned short*)(ws + (size_t)62914560);    // 16 MB  [4096][2048] bf16
  unsigned short* Vt   = (unsigned short*)(ws + (size_t)79691776);    //  4 MB  [4][128][4096] bf16

  k_cast_bf16<<<8192, 256, 0, stream>>>(hid, Xb, 2097152);
  k_transpose_bf16<<<dim3(32, 32), 256, 0, stream>>>(Wq, Wt, 2048, 2048);
  k_transpose_bf16<<<dim3(32, 8), 256, 0, stream>>>(Wk, Wt + (size_t)2048 * 2048, 2048, 512);
  k_transpose_bf16<<<dim3(32, 8), 256, 0, stream>>>(Wv, Wt + (size_t)2560 * 2048, 2048, 512);
  k_transpose_bf16<<<dim3(32, 32), 256, 0, stream>>>(Wo, Wot, 2048, 2048);
  k_gemm8<0><<<384, 512, 0, stream>>>(Xb, Wt, QKV, 4096, 3072, 2048, 16, 24);
  k_rope<<<5120, 256, 0, stream>>>(QKV, cosp, sinp);
  k_transpose_v<<<dim3(64, 8), 256, 0, stream>>>(QKV, Vt);
  k_attn<<<dim3(16, 16), 512, 0, stream>>>(QKV, Vt, gate, Oatt);
  k_gemm8<1><<<256, 512, 0, stream>>>(Oatt, Wot, out, 4096, 2048, 2048, 16, 16);
}

// Round 8
// 260.035 us; speedup vs baseline: 1.0806x; 1.0806x over previous
//
#include <hip/hip_runtime.h>
#include <math.h>

#define S_LEN 4096
#define DMODEL 2048
#define NH 16
#define NKVH 4
#define HD 128
#define LDQKV 3072   // NH*HD + 2*NKVH*HD

typedef __attribute__((ext_vector_type(4))) float f32x4;
typedef __attribute__((ext_vector_type(8))) short bf16x8;
typedef __attribute__((ext_vector_type(4))) unsigned short us4;

static __device__ __forceinline__ unsigned short f2bf(float f) {
  unsigned int u = __builtin_bit_cast(unsigned int, f);
  u += 0x7fffu + ((u >> 16) & 1u);
  return (unsigned short)(u >> 16);
}
static __device__ __forceinline__ float bf2f(unsigned short h) {
  unsigned int u = ((unsigned int)h) << 16;
  return __builtin_bit_cast(float, u);
}
static __device__ __forceinline__ unsigned int cvt_pk_bf16(float lo, float hi) {
  unsigned int r;
  asm("v_cvt_pk_bf16_f32 %0, %1, %2" : "=v"(r) : "v"(lo), "v"(hi));
  return r;
}

#define GLDS16(g, l) __builtin_amdgcn_global_load_lds( \
    (__attribute__((address_space(1))) void*)(g), \
    (__attribute__((address_space(3))) void*)(l), 16, 0, 0)

// ---------------- prep kernels ----------------

__global__ __launch_bounds__(256) void k_cast_bf16(const float* __restrict__ src,
                                                   unsigned short* __restrict__ dst, int n4) {
  int i = blockIdx.x * 256 + threadIdx.x;
  if (i >= n4) return;
  const float4* s = (const float4*)src;
  float4 v = s[i];
  us4 o = { f2bf(v.x), f2bf(v.y), f2bf(v.z), f2bf(v.w) };
  *(us4*)(dst + (size_t)i * 4) = o;
}

// merged weight transposes: dst[n*2048+k] = bf16(src[k*N+n])
// blocks: [0,1024) Wq->Wt ; [1024,1280) Wk->Wt+2048*2048 ; [1280,1536) Wv->Wt+2560*2048 ;
//         [1536,2560) Wo->Wot
__global__ __launch_bounds__(256) void k_transpose_w(
    const float* __restrict__ Wq, const float* __restrict__ Wk,
    const float* __restrict__ Wv, const float* __restrict__ Wo,
    unsigned short* __restrict__ Wt, unsigned short* __restrict__ Wot) {
  __shared__ float tile[64][65];
  const int b = blockIdx.x;
  const float* src;
  unsigned short* dst;
  int N, c;
  if (b < 1024)      { src = Wq; dst = Wt;                         N = 2048; c = b; }
  else if (b < 1280) { src = Wk; dst = Wt + (size_t)2048 * 2048;   N = 512;  c = b - 1024; }
  else if (b < 1536) { src = Wv; dst = Wt + (size_t)2560 * 2048;   N = 512;  c = b - 1280; }
  else               { src = Wo; dst = Wot;                        N = 2048; c = b - 1536; }
  const int k0 = (c & 31) * 64, n0 = (c >> 5) * 64;
  const int t = threadIdx.x;
#pragma unroll
  for (int i = 0; i < 16; ++i) {
    int idx = t + i * 256;
    int r = idx >> 6, cc = idx & 63;
    tile[r][cc] = src[(size_t)(k0 + r) * N + n0 + cc];
  }
  __syncthreads();
#pragma unroll
  for (int i = 0; i < 16; ++i) {
    int idx = t + i * 256;
    int r = idx >> 6, cc = idx & 63;
    dst[(size_t)(n0 + r) * 2048 + k0 + cc] = f2bf(tile[cc][r]);
  }
}

// merged RoPE (blocks [0,5120)) + V-transpose (blocks [5120,5632))
// RoPE: in-place on Q (cols 0..2047, scaled by log2e/sqrt(HD)) and K (2048..2559).
// V-transpose: Vt[(kvh*128+d)*S + blk*64 + cc] = QKV[blk*64 + pi(cc)][2560+kvh*128+d],
// pi(cc) = (cc&3)*16 + (cc>>2)  — k-permutation matching the P storage layout.
__global__ __launch_bounds__(256) void k_rope_tv(unsigned short* __restrict__ QKV,
    const float* __restrict__ cp, const float* __restrict__ sp,
    unsigned short* __restrict__ Vt) {
  __shared__ unsigned short tile[64][72];
  const int b = blockIdx.x, t = threadIdx.x;
  if (b < 5120) {
    int gid = b * 256 + t;     // S*20*16 total
    int d4 = (gid & 15) * 4;
    int hh = (gid >> 4) % 20;
    int s = gid / 320;
    int col = hh < NH ? hh * HD : DMODEL + (hh - NH) * HD;
    float qs = hh < NH ? 0.12751589341664477f : 1.0f;  // log2e/sqrt(128) for Q heads
    size_t base = (size_t)s * LDQKV + col + d4;
    us4 x1 = *(us4*)(QKV + base);
    us4 x2 = *(us4*)(QKV + base + 64);
    float4 c = *(const float4*)(cp + s * HD + d4);
    float4 sn = *(const float4*)(sp + s * HD + d4);
    us4 o1, o2;
    o1[0] = f2bf((bf2f(x1[0]) * c.x - bf2f(x2[0]) * sn.x) * qs);
    o1[1] = f2bf((bf2f(x1[1]) * c.y - bf2f(x2[1]) * sn.y) * qs);
    o1[2] = f2bf((bf2f(x1[2]) * c.z - bf2f(x2[2]) * sn.z) * qs);
    o1[3] = f2bf((bf2f(x1[3]) * c.w - bf2f(x2[3]) * sn.w) * qs);
    o2[0] = f2bf((bf2f(x2[0]) * c.x + bf2f(x1[0]) * sn.x) * qs);
    o2[1] = f2bf((bf2f(x2[1]) * c.y + bf2f(x1[1]) * sn.y) * qs);
    o2[2] = f2bf((bf2f(x2[2]) * c.z + bf2f(x1[2]) * sn.z) * qs);
    o2[3] = f2bf((bf2f(x2[3]) * c.w + bf2f(x1[3]) * sn.w) * qs);
    *(us4*)(QKV + base) = o1;
    *(us4*)(QKV + base + 64) = o2;
  } else {
    const int bb = b - 5120;           // original grid (64, 8)
    const int s0 = (bb & 63) * 64, c0 = (bb >> 6) * 64;
#pragma unroll
    for (int i = 0; i < 16; ++i) {
      int idx = t + i * 256;
      int r = idx >> 6, cc = idx & 63;
      tile[r][cc] = QKV[(size_t)(s0 + r) * LDQKV + DMODEL + NKVH * HD + c0 + cc];
    }
    __syncthreads();
#pragma unroll
    for (int i = 0; i < 16; ++i) {
      int idx = t + i * 256;
      int r = idx >> 6, cc = idx & 63;
      int pc = (cc & 3) * 16 + (cc >> 2);
      Vt[(size_t)(c0 + r) * S_LEN + s0 + cc] = tile[pc][r];
    }
  }
}

// ---------------- GEMM: C[M][N] = A[M][K] * Bt[N][K]^T ----------------
// 128x128 tile, BK=32, 4 waves (each 64x64), source-swizzled global_load_lds.
// Proven m97-class structure (~900 TF) — structural ceiling for this shape.

template<int OUTF32>
__global__ __launch_bounds__(256) void k_gemm_bt(
    const unsigned short* __restrict__ A, const unsigned short* __restrict__ Bt,
    void* __restrict__ Cp, int M, int N, int K) {
  __shared__ __attribute__((aligned(16))) unsigned short As[128 * 32];
  __shared__ __attribute__((aligned(16))) unsigned short Bs[128 * 32];
  const int t = threadIdx.x;
  const int wave = t >> 6, lane = t & 63;
  const int lr = lane & 15, lg = lane >> 4;
  const int bm = blockIdx.x * 128, bn = blockIdx.y * 128;
  const int wr = (wave >> 1) * 64, wc = (wave & 1) * 64;
  f32x4 acc[4][4];
#pragma unroll
  for (int i = 0; i < 4; ++i)
#pragma unroll
    for (int j = 0; j < 4; ++j) acc[i][j] = (f32x4){0.f, 0.f, 0.f, 0.f};

  for (int k0 = 0; k0 < K; k0 += 32) {
    __syncthreads();
#pragma unroll
    for (int i = 0; i < 2; ++i) {
      const int cb = (wave * 2 + i) * 64;
      const int c = cb + lane;
      const int row = c >> 2, kc = c & 3;
      const int ksw = (kc ^ (row & 3)) * 8;
      GLDS16(A + (size_t)(bm + row) * K + k0 + ksw, (char*)As + cb * 16);
      GLDS16(Bt + (size_t)(bn + row) * K + k0 + ksw, (char*)Bs + cb * 16);
    }
    asm volatile("s_waitcnt vmcnt(0)" ::: "memory");
    __syncthreads();
    bf16x8 af[4], bfr[4];
#pragma unroll
    for (int mi = 0; mi < 4; ++mi) {
      const int row = wr + mi * 16 + lr;
      af[mi] = *(const bf16x8*)(As + row * 32 + ((lg ^ (lr & 3)) * 8));
    }
#pragma unroll
    for (int ni = 0; ni < 4; ++ni) {
      const int row = wc + ni * 16 + lr;
      bfr[ni] = *(const bf16x8*)(Bs + row * 32 + ((lg ^ (lr & 3)) * 8));
    }
#pragma unroll
    for (int mi = 0; mi < 4; ++mi)
#pragma unroll
      for (int ni = 0; ni < 4; ++ni)
        acc[mi][ni] = __builtin_amdgcn_mfma_f32_16x16x32_bf16(af[mi], bfr[ni], acc[mi][ni], 0, 0, 0);
  }
#pragma unroll
  for (int mi = 0; mi < 4; ++mi)
#pragma unroll
    for (int ni = 0; ni < 4; ++ni)
#pragma unroll
      for (int r = 0; r < 4; ++r) {
        const int m = bm + wr + mi * 16 + lg * 4 + r;
        const int n = bn + wc + ni * 16 + lr;
        if (OUTF32) ((float*)Cp)[(size_t)m * N + n] = acc[mi][ni][r];
        else ((unsigned short*)Cp)[(size_t)m * N + n] = f2bf(acc[mi][ni][r]);
      }
}

// ---------------- fused causal gated attention (v7: 8-wave, KVBLK=128) ----------------
// grid (16, NH), 512 threads. Block bx serves q-super-tiles A=31-bx then B=bx
// (128 rows each); KV tiles are 128x128 (K and V^T), double-buffered.
// No manual LDS fences: P is per-wave, the compiler emits exact counted lgkmcnt
// and may overlap hh=1's exp/pack VALU with hh=0's PV MFMA.

#define STAGE_KV(kt_, buf_) do { \
  const int kv0_ = (kt_) * 128; \
  _Pragma("unroll") \
  for (int i_ = 0; i_ < 4; ++i_) { \
    const int cb_ = (wave * 4 + i_) * 64; \
    const int c_ = cb_ + lane; \
    const int row_ = c_ >> 4, kc_ = c_ & 15; \
    const int sw_ = (kc_ ^ (row_ & 7)) * 8; \
    GLDS16(Kp + (size_t)(kv0_ + row_) * LDQKV + sw_, (char*)Ks[buf_] + cb_ * 16); \
    GLDS16(Vp + (size_t)row_ * S_LEN + kv0_ + sw_, (char*)Vs[buf_] + cb_ * 16); \
  } \
} while (0)

__device__ __forceinline__ void qkt_one(const unsigned short* Kb,
    const bf16x8* qf, f32x4* sc, int lr, int lg) {
  __builtin_amdgcn_s_setprio(1);
#pragma unroll
  for (int cf = 0; cf < 8; ++cf) {
    sc[cf] = (f32x4){0.f, 0.f, 0.f, 0.f};
    const int row = cf * 16 + lr;
#pragma unroll
    for (int ks = 0; ks < 4; ++ks) {
      bf16x8 kb = *(const bf16x8*)(Kb + row * 128 + (((ks * 4 + lg) ^ (lr & 7)) * 8));
      sc[cf] = __builtin_amdgcn_mfma_f32_16x16x32_bf16(qf[ks], kb, sc[cf], 0, 0, 0);
    }
  }
  __builtin_amdgcn_s_setprio(0);
}

template<bool DIAG>
__device__ __forceinline__ void softmax_pv(
    f32x4* sc, const unsigned short* Vb, unsigned short (*PsW)[72],
    const float* g8, int kv0, int qbase,
    f32x4* acc, f32x4& acc_s, float* mrow, int lr, int lg,
    const bf16x8 vb_ones) {
  if (DIAG) {
#pragma unroll
    for (int cf = 0; cf < 8; ++cf) {
      const int kpos = kv0 + cf * 16 + lr;
#pragma unroll
      for (int r = 0; r < 4; ++r)
        sc[cf][r] = (kpos <= qbase + r) ? sc[cf][r] : -3e38f;
    }
  }
  float lmax[4];
#pragma unroll
  for (int r = 0; r < 4; ++r) {
    float a = fmaxf(fmaxf(sc[0][r], sc[1][r]), fmaxf(sc[2][r], sc[3][r]));
    float b = fmaxf(fmaxf(sc[4][r], sc[5][r]), fmaxf(sc[6][r], sc[7][r]));
    lmax[r] = fmaxf(a, b);
  }
  bool need = (lmax[0] > mrow[0] + 11.5416f) | (lmax[1] > mrow[1] + 11.5416f) |
              (lmax[2] > mrow[2] + 11.5416f) | (lmax[3] > mrow[3] + 11.5416f);
  if (__any(need)) {
    float tm[4] = {lmax[0], lmax[1], lmax[2], lmax[3]};
#pragma unroll
    for (int off = 8; off; off >>= 1)
#pragma unroll
      for (int r = 0; r < 4; ++r) tm[r] = fmaxf(tm[r], __shfl_xor(tm[r], off));
#pragma unroll
    for (int r = 0; r < 4; ++r) {
      const float mn = fmaxf(mrow[r], tm[r]);
      const float alpha = __builtin_amdgcn_exp2f(mrow[r] - mn);
      mrow[r] = mn;
#pragma unroll
      for (int j = 0; j < 8; ++j) acc[j][r] *= alpha;
      acc_s[r] *= alpha;
    }
  }
  // two 64-col halves: exp+pack+write P, then PV for that half.
#pragma unroll
  for (int hh = 0; hh < 2; ++hh) {
    const f32x4* s4 = sc + hh * 4;
    const float* g4 = g8 + hh * 4;
#pragma unroll
    for (int r = 0; r < 4; ++r) {
      float p0 = __builtin_amdgcn_exp2f(s4[0][r] - mrow[r]) * g4[0];
      float p1 = __builtin_amdgcn_exp2f(s4[1][r] - mrow[r]) * g4[1];
      float p2 = __builtin_amdgcn_exp2f(s4[2][r] - mrow[r]) * g4[2];
      float p3 = __builtin_amdgcn_exp2f(s4[3][r] - mrow[r]) * g4[3];
      uint2 pk = { cvt_pk_bf16(p0, p1), cvt_pk_bf16(p2, p3) };
      *(uint2*)(&PsW[lg * 4 + r][lr * 4]) = pk;
    }
    __builtin_amdgcn_s_setprio(1);
#pragma unroll
    for (int ks = 0; ks < 2; ++ks) {
      bf16x8 pa = *(const bf16x8*)(&PsW[lr][ks * 32 + lg * 8]);
#pragma unroll
      for (int j = 0; j < 8; ++j) {
        const int d = j * 16 + lr;
        bf16x8 vb = *(const bf16x8*)(Vb + d * 128 + ((hh * 8 + ((ks * 4 + lg) ^ (lr & 7))) * 8));
        acc[j] = __builtin_amdgcn_mfma_f32_16x16x32_bf16(pa, vb, acc[j], 0, 0, 0);
      }
      acc_s = __builtin_amdgcn_mfma_f32_16x16x32_bf16(pa, vb_ones, acc_s, 0, 0, 0);
    }
    __builtin_amdgcn_s_setprio(0);
  }
}

__global__ __launch_bounds__(512) void k_attn(
    const unsigned short* __restrict__ QKV, const unsigned short* __restrict__ Vt,
    const float* __restrict__ gate, unsigned short* __restrict__ Oattn) {
  __shared__ __attribute__((aligned(16))) unsigned short Ks[2][128 * 128];
  __shared__ __attribute__((aligned(16))) unsigned short Vs[2][128 * 128];
  __shared__ __attribute__((aligned(16))) unsigned short Ps[8][16][72];
  const int h = blockIdx.y, kvh = h >> 2;
  const int bx = blockIdx.x;           // 0..15
  const int t = threadIdx.x, wave = t >> 6, lane = t & 63;
  const int lr = lane & 15, lg = lane >> 4;
  const unsigned short* Qp = QKV + h * HD;
  const unsigned short* Kp = QKV + DMODEL + kvh * HD;
  const unsigned short* Vp = Vt + (size_t)kvh * HD * S_LEN;
  unsigned short (*PsW)[72] = Ps[wave];
  bf16x8 vb_ones;
  {
    const short one = (short)0x3F80, z = 0;
    const short e = (lr == 0) ? one : z;
    vb_ones = (bf16x8){e, e, e, e, e, e, e, e};
  }

  for (int half = 0; half < 2; ++half) {
    const int st = half ? bx : (31 - bx);   // super-tile (128 rows), heavy first
    const int q0 = st * 128;
    const int nt = st + 1;                  // KV tiles (128 wide) 0..nt-1
    const int qbase = q0 + wave * 16 + lg * 4;

    bf16x8 qf[4];
    {
      const size_t qoff = (size_t)(q0 + wave * 16 + lr) * LDQKV;
#pragma unroll
      for (int ks = 0; ks < 4; ++ks)
        qf[ks] = *(const bf16x8*)(Qp + qoff + ks * 32 + lg * 8);
    }
    f32x4 acc[8];
#pragma unroll
    for (int j = 0; j < 8; ++j) acc[j] = (f32x4){0.f, 0.f, 0.f, 0.f};
    f32x4 acc_s = (f32x4){0.f, 0.f, 0.f, 0.f};
    float mrow[4] = {-3e38f, -3e38f, -3e38f, -3e38f};
    f32x4 sc[8];
    float g8[8];

    __builtin_amdgcn_s_barrier();        // protect buf0 from previous half's reads
    STAGE_KV(0, 0);

    int kt = 0;
    for (; kt < nt - 1; ++kt) {
      STAGE_KV(kt + 1, (kt + 1) & 1);
      asm volatile("s_waitcnt vmcnt(8)" ::: "memory");
      __builtin_amdgcn_s_barrier();
#pragma unroll
      for (int cf = 0; cf < 8; ++cf) g8[cf] = gate[kt * 128 + cf * 16 + lr];
      qkt_one(Ks[kt & 1], qf, sc, lr, lg);
      softmax_pv<false>(sc, Vs[kt & 1], PsW, g8, kt * 128, qbase, acc, acc_s, mrow, lr, lg, vb_ones);
      __builtin_amdgcn_s_barrier();
    }
    // diagonal tile (kv0 == q0)
    {
      asm volatile("s_waitcnt vmcnt(0)" ::: "memory");
      __builtin_amdgcn_s_barrier();
#pragma unroll
      for (int cf = 0; cf < 8; ++cf) g8[cf] = gate[kt * 128 + cf * 16 + lr];
      qkt_one(Ks[kt & 1], qf, sc, lr, lg);
      softmax_pv<true>(sc, Vs[kt & 1], PsW, g8, kt * 128, qbase, acc, acc_s, mrow, lr, lg, vb_ones);
    }

    float inv[4];
#pragma unroll
    for (int r = 0; r < 4; ++r)
      inv[r] = 1.0f / __shfl(acc_s[r], lane & 48);
#pragma unroll
    for (int j = 0; j < 8; ++j)
#pragma unroll
      for (int r = 0; r < 4; ++r)
        Oattn[(size_t)(qbase + r) * DMODEL + h * HD + j * 16 + lr] = f2bf(acc[j][r] * inv[r]);
  }
}

// ---------------- launch ----------------

extern "C" void kernel_launch(void* const* d_in, const int* in_sizes, int n_in,
                              void* d_out, int out_size, void* d_ws, size_t ws_size,
                              hipStream_t stream) {
  (void)in_sizes; (void)n_in; (void)out_size; (void)ws_size;
  const float* hid  = (const float*)d_in[0];
  // d_in[1] = attention_mask (pure causal; recomputed inline, never read)
  const float* cosp = (const float*)d_in[2];
  const float* sinp = (const float*)d_in[3];
  const float* gate = (const float*)d_in[4];
  const float* Wq   = (const float*)d_in[5];
  const float* Wk   = (const float*)d_in[6];
  const float* Wv   = (const float*)d_in[7];
  const float* Wo   = (const float*)d_in[8];
  float* out = (float*)d_out;
  char* ws = (char*)d_ws;
  unsigned short* Xb   = (unsigned short*)(ws);                       // 16 MB  [4096][2048] bf16
  unsigned short* Wt   = (unsigned short*)(ws + (size_t)16777216);    // 12 MB  [3072][2048] bf16 (Wq|Wk|Wv)^T
  unsigned short* Wot  = (unsigned short*)(ws + (size_t)29360128);    //  8 MB  [2048][2048] bf16 Wo^T
  unsigned short* QKV  = (unsigned short*)(ws + (size_t)37748736);    // 24 MB  [4096][3072] bf16
  unsigned short* Oatt = (unsigned short*)(ws + (size_t)62914560);    // 16 MB  [4096][2048] bf16
  unsigned short* Vt   = (unsigned short*)(ws + (size_t)79691776);    //  4 MB  [4][128][4096] bf16

  k_cast_bf16<<<8192, 256, 0, stream>>>(hid, Xb, 2097152);
  k_transpose_w<<<2560, 256, 0, stream>>>(Wq, Wk, Wv, Wo, Wt, Wot);
  k_gemm_bt<0><<<dim3(32, 24), 256, 0, stream>>>(Xb, Wt, QKV, 4096, 3072, 2048);
  k_rope_tv<<<5632, 256, 0, stream>>>(QKV, cosp, sinp, Vt);
  k_attn<<<dim3(16, 16), 512, 0, stream>>>(QKV, Vt, gate, Oatt);
  k_gemm_bt<1><<<dim3(32, 16), 256, 0, stream>>>(Oatt, Wot, out, 4096, 2048, 2048);
}

// Round 10
// 248.500 us; speedup vs baseline: 1.1308x; 1.0464x over previous
//
#include <hip/hip_runtime.h>
#include <math.h>

#define S_LEN 4096
#define DMODEL 2048
#define NH 16
#define NKVH 4
#define HD 128
#define LDQKV 3072   // NH*HD + 2*NKVH*HD

typedef __attribute__((ext_vector_type(4))) float f32x4;
typedef __attribute__((ext_vector_type(8))) short bf16x8;
typedef __attribute__((ext_vector_type(4))) unsigned short us4;

static __device__ __forceinline__ unsigned short f2bf(float f) {
  unsigned int u = __builtin_bit_cast(unsigned int, f);
  u += 0x7fffu + ((u >> 16) & 1u);
  return (unsigned short)(u >> 16);
}
static __device__ __forceinline__ float bf2f(unsigned short h) {
  unsigned int u = ((unsigned int)h) << 16;
  return __builtin_bit_cast(float, u);
}
static __device__ __forceinline__ unsigned int cvt_pk_bf16(float lo, float hi) {
  unsigned int r;
  asm("v_cvt_pk_bf16_f32 %0, %1, %2" : "=v"(r) : "v"(lo), "v"(hi));
  return r;
}

#define GLDS16(g, l) __builtin_amdgcn_global_load_lds( \
    (__attribute__((address_space(1))) void*)(g), \
    (__attribute__((address_space(3))) void*)(l), 16, 0, 0)

// ---------------- prep: cast hidden to bf16 + transpose all weights ----------------
// blocks [0,8192): cast; [8192,9216) Wq; [9216,9472) Wk; [9472,9728) Wv; [9728,10752) Wo

__global__ __launch_bounds__(256) void k_prep(
    const float* __restrict__ hid, unsigned short* __restrict__ Xb,
    const float* __restrict__ Wq, const float* __restrict__ Wk,
    const float* __restrict__ Wv, const float* __restrict__ Wo,
    unsigned short* __restrict__ Wt, unsigned short* __restrict__ Wot) {
  __shared__ float tile[64][65];
  const int b = blockIdx.x, t = threadIdx.x;
  if (b < 8192) {
    int i = b * 256 + t;
    const float4* s = (const float4*)hid;
    float4 v = s[i];
    us4 o = { f2bf(v.x), f2bf(v.y), f2bf(v.z), f2bf(v.w) };
    *(us4*)(Xb + (size_t)i * 4) = o;
    return;
  }
  const int bb = b - 8192;
  const float* src;
  unsigned short* dst;
  int N, c;
  if (bb < 1024)      { src = Wq; dst = Wt;                       N = 2048; c = bb; }
  else if (bb < 1280) { src = Wk; dst = Wt + (size_t)2048 * 2048; N = 512;  c = bb - 1024; }
  else if (bb < 1536) { src = Wv; dst = Wt + (size_t)2560 * 2048; N = 512;  c = bb - 1280; }
  else                { src = Wo; dst = Wot;                      N = 2048; c = bb - 1536; }
  const int k0 = (c & 31) * 64, n0 = (c >> 5) * 64;
#pragma unroll
  for (int i = 0; i < 16; ++i) {
    int idx = t + i * 256;
    int r = idx >> 6, cc = idx & 63;
    tile[r][cc] = src[(size_t)(k0 + r) * N + n0 + cc];
  }
  __syncthreads();
#pragma unroll
  for (int i = 0; i < 16; ++i) {
    int idx = t + i * 256;
    int r = idx >> 6, cc = idx & 63;
    dst[(size_t)(n0 + r) * 2048 + k0 + cc] = f2bf(tile[cc][r]);
  }
}

// ---------------- V-transpose (permuted) ----------------
// Vt[(c0+r)*S + s0+cc] = QKV[s0 + pi(cc)][2560 + c0 + r], pi(cc)=(cc&3)*16+(cc>>2)

__global__ __launch_bounds__(256) void k_vt(
    const unsigned short* __restrict__ QKV, unsigned short* __restrict__ Vt) {
  __shared__ unsigned short tile[64][72];
  const int b = blockIdx.x, t = threadIdx.x;
  const int s0 = (b & 63) * 64, c0 = (b >> 6) * 64;
#pragma unroll
  for (int i = 0; i < 16; ++i) {
    int idx = t + i * 256;
    int r = idx >> 6, cc = idx & 63;
    tile[r][cc] = QKV[(size_t)(s0 + r) * LDQKV + DMODEL + NKVH * HD + c0 + cc];
  }
  __syncthreads();
#pragma unroll
  for (int i = 0; i < 16; ++i) {
    int idx = t + i * 256;
    int r = idx >> 6, cc = idx & 63;
    int pc = (cc & 3) * 16 + (cc >> 2);
    Vt[(size_t)(c0 + r) * S_LEN + s0 + cc] = tile[pc][r];
  }
}

// ---------------- GEMM: C[M][N] = A[M][K] * Bt[N][K]^T ----------------
// 128x128 tile, BK=32, 4 waves M-split (32 rows x 128 cols each).
// MODE 1: QKV epilogue (RoPE on Q/K in f32, bf16 out); MODE 2: f32 out.

template<int MODE>
__global__ __launch_bounds__(256) void k_gemm_bt(
    const unsigned short* __restrict__ A, const unsigned short* __restrict__ Bt,
    void* __restrict__ Cp, int M, int N, int K,
    const float* __restrict__ cp, const float* __restrict__ sp) {
  __shared__ __attribute__((aligned(16))) unsigned short As[128 * 32];
  __shared__ __attribute__((aligned(16))) unsigned short Bs[128 * 32];
  const int t = threadIdx.x;
  const int wave = t >> 6, lane = t & 63;
  const int lr = lane & 15, lg = lane >> 4;
  const int bm = blockIdx.x * 128, bn = blockIdx.y * 128;
  const int wr = wave * 32;
  f32x4 acc[2][8];
#pragma unroll
  for (int i = 0; i < 2; ++i)
#pragma unroll
    for (int j = 0; j < 8; ++j) acc[i][j] = (f32x4){0.f, 0.f, 0.f, 0.f};

  for (int k0 = 0; k0 < K; k0 += 32) {
    __syncthreads();
#pragma unroll
    for (int i = 0; i < 2; ++i) {
      const int cb = (wave * 2 + i) * 64;
      const int c = cb + lane;
      const int row = c >> 2, kc = c & 3;
      const int ksw = (kc ^ (row & 3)) * 8;
      GLDS16(A + (size_t)(bm + row) * K + k0 + ksw, (char*)As + cb * 16);
      GLDS16(Bt + (size_t)(bn + row) * K + k0 + ksw, (char*)Bs + cb * 16);
    }
    asm volatile("s_waitcnt vmcnt(0)" ::: "memory");
    __syncthreads();
    bf16x8 af[2], bfr[8];
#pragma unroll
    for (int mi = 0; mi < 2; ++mi) {
      const int row = wr + mi * 16 + lr;
      af[mi] = *(const bf16x8*)(As + row * 32 + ((lg ^ (lr & 3)) * 8));
    }
#pragma unroll
    for (int ni = 0; ni < 8; ++ni) {
      const int row = ni * 16 + lr;
      bfr[ni] = *(const bf16x8*)(Bs + row * 32 + ((lg ^ (lr & 3)) * 8));
    }
#pragma unroll
    for (int mi = 0; mi < 2; ++mi)
#pragma unroll
      for (int ni = 0; ni < 8; ++ni)
        acc[mi][ni] = __builtin_amdgcn_mfma_f32_16x16x32_bf16(af[mi], bfr[ni], acc[mi][ni], 0, 0, 0);
  }

  if (MODE == 1 && bn < NKVH * HD + DMODEL) {
    // Q (bn<2048) or K (2048<=bn<2560) head tile: RoPE in f32.
    // d and d+64 live in the same wave (partner fragment ni+4); cos/sin period 64.
    const float qs = bn < DMODEL ? 0.12751589341664477f : 1.0f;  // log2e/sqrt(128) on Q
    unsigned short* o = (unsigned short*)Cp;
#pragma unroll
    for (int mi = 0; mi < 2; ++mi)
#pragma unroll
      for (int r = 0; r < 4; ++r) {
        const int m = bm + wr + mi * 16 + lg * 4 + r;
#pragma unroll
        for (int ni = 0; ni < 4; ++ni) {
          const int d = ni * 16 + lr;
          const float c = cp[m * HD + d], s = sp[m * HD + d];
          const float x1 = acc[mi][ni][r], x2 = acc[mi][ni + 4][r];
          o[(size_t)m * N + bn + d]      = f2bf((x1 * c - x2 * s) * qs);
          o[(size_t)m * N + bn + d + 64] = f2bf((x2 * c + x1 * s) * qs);
        }
      }
    return;
  }
#pragma unroll
  for (int mi = 0; mi < 2; ++mi)
#pragma unroll
    for (int ni = 0; ni < 8; ++ni)
#pragma unroll
      for (int r = 0; r < 4; ++r) {
        const int m = bm + wr + mi * 16 + lg * 4 + r;
        const int n = bn + ni * 16 + lr;
        if (MODE == 2) ((float*)Cp)[(size_t)m * N + n] = acc[mi][ni][r];
        else ((unsigned short*)Cp)[(size_t)m * N + n] = f2bf(acc[mi][ni][r]);
      }
}

// ---------------- fused causal gated attention (round-8 kernel, unchanged) ----------------
// grid (16, NH), 512 threads, 8 waves x 16 q-rows, KVBLK=128 double-buffered.

#define STAGE_KV(kt_, buf_) do { \
  const int kv0_ = (kt_) * 128; \
  _Pragma("unroll") \
  for (int i_ = 0; i_ < 4; ++i_) { \
    const int cb_ = (wave * 4 + i_) * 64; \
    const int c_ = cb_ + lane; \
    const int row_ = c_ >> 4, kc_ = c_ & 15; \
    const int sw_ = (kc_ ^ (row_ & 7)) * 8; \
    GLDS16(Kp + (size_t)(kv0_ + row_) * LDQKV + sw_, (char*)Ks[buf_] + cb_ * 16); \
    GLDS16(Vp + (size_t)row_ * S_LEN + kv0_ + sw_, (char*)Vs[buf_] + cb_ * 16); \
  } \
} while (0)

__device__ __forceinline__ void qkt_one(const unsigned short* Kb,
    const bf16x8* qf, f32x4* sc, int lr, int lg) {
  __builtin_amdgcn_s_setprio(1);
#pragma unroll
  for (int cf = 0; cf < 8; ++cf) {
    sc[cf] = (f32x4){0.f, 0.f, 0.f, 0.f};
    const int row = cf * 16 + lr;
#pragma unroll
    for (int ks = 0; ks < 4; ++ks) {
      bf16x8 kb = *(const bf16x8*)(Kb + row * 128 + (((ks * 4 + lg) ^ (lr & 7)) * 8));
      sc[cf] = __builtin_amdgcn_mfma_f32_16x16x32_bf16(qf[ks], kb, sc[cf], 0, 0, 0);
    }
  }
  __builtin_amdgcn_s_setprio(0);
}

template<bool DIAG>
__device__ __forceinline__ void softmax_pv(
    f32x4* sc, const unsigned short* Vb, unsigned short (*PsW)[72],
    const float* g8, int kv0, int qbase,
    f32x4* acc, f32x4& acc_s, float* mrow, int lr, int lg,
    const bf16x8 vb_ones) {
  if (DIAG) {
#pragma unroll
    for (int cf = 0; cf < 8; ++cf) {
      const int kpos = kv0 + cf * 16 + lr;
#pragma unroll
      for (int r = 0; r < 4; ++r)
        sc[cf][r] = (kpos <= qbase + r) ? sc[cf][r] : -3e38f;
    }
  }
  float lmax[4];
#pragma unroll
  for (int r = 0; r < 4; ++r) {
    float a = fmaxf(fmaxf(sc[0][r], sc[1][r]), fmaxf(sc[2][r], sc[3][r]));
    float b = fmaxf(fmaxf(sc[4][r], sc[5][r]), fmaxf(sc[6][r], sc[7][r]));
    lmax[r] = fmaxf(a, b);
  }
  bool need = (lmax[0] > mrow[0] + 11.5416f) | (lmax[1] > mrow[1] + 11.5416f) |
              (lmax[2] > mrow[2] + 11.5416f) | (lmax[3] > mrow[3] + 11.5416f);
  if (__any(need)) {
    float tm[4] = {lmax[0], lmax[1], lmax[2], lmax[3]};
#pragma unroll
    for (int off = 8; off; off >>= 1)
#pragma unroll
      for (int r = 0; r < 4; ++r) tm[r] = fmaxf(tm[r], __shfl_xor(tm[r], off));
#pragma unroll
    for (int r = 0; r < 4; ++r) {
      const float mn = fmaxf(mrow[r], tm[r]);
      const float alpha = __builtin_amdgcn_exp2f(mrow[r] - mn);
      mrow[r] = mn;
#pragma unroll
      for (int j = 0; j < 8; ++j) acc[j][r] *= alpha;
      acc_s[r] *= alpha;
    }
  }
  // two 64-col halves: exp+pack+write P, then PV for that half.
#pragma unroll
  for (int hh = 0; hh < 2; ++hh) {
    const f32x4* s4 = sc + hh * 4;
    const float* g4 = g8 + hh * 4;
#pragma unroll
    for (int r = 0; r < 4; ++r) {
      float p0 = __builtin_amdgcn_exp2f(s4[0][r] - mrow[r]) * g4[0];
      float p1 = __builtin_amdgcn_exp2f(s4[1][r] - mrow[r]) * g4[1];
      float p2 = __builtin_amdgcn_exp2f(s4[2][r] - mrow[r]) * g4[2];
      float p3 = __builtin_amdgcn_exp2f(s4[3][r] - mrow[r]) * g4[3];
      uint2 pk = { cvt_pk_bf16(p0, p1), cvt_pk_bf16(p2, p3) };
      *(uint2*)(&PsW[lg * 4 + r][lr * 4]) = pk;
    }
    __builtin_amdgcn_s_setprio(1);
#pragma unroll
    for (int ks = 0; ks < 2; ++ks) {
      bf16x8 pa = *(const bf16x8*)(&PsW[lr][ks * 32 + lg * 8]);
#pragma unroll
      for (int j = 0; j < 8; ++j) {
        const int d = j * 16 + lr;
        bf16x8 vb = *(const bf16x8*)(Vb + d * 128 + ((hh * 8 + ((ks * 4 + lg) ^ (lr & 7))) * 8));
        acc[j] = __builtin_amdgcn_mfma_f32_16x16x32_bf16(pa, vb, acc[j], 0, 0, 0);
      }
      acc_s = __builtin_amdgcn_mfma_f32_16x16x32_bf16(pa, vb_ones, acc_s, 0, 0, 0);
    }
    __builtin_amdgcn_s_setprio(0);
  }
}

__global__ __launch_bounds__(512) void k_attn(
    const unsigned short* __restrict__ QKV, const unsigned short* __restrict__ Vt,
    const float* __restrict__ gate, unsigned short* __restrict__ Oattn) {
  __shared__ __attribute__((aligned(16))) unsigned short Ks[2][128 * 128];
  __shared__ __attribute__((aligned(16))) unsigned short Vs[2][128 * 128];
  __shared__ __attribute__((aligned(16))) unsigned short Ps[8][16][72];
  const int h = blockIdx.y, kvh = h >> 2;
  const int bx = blockIdx.x;           // 0..15
  const int t = threadIdx.x, wave = t >> 6, lane = t & 63;
  const int lr = lane & 15, lg = lane >> 4;
  const unsigned short* Qp = QKV + h * HD;
  const unsigned short* Kp = QKV + DMODEL + kvh * HD;
  const unsigned short* Vp = Vt + (size_t)kvh * HD * S_LEN;
  unsigned short (*PsW)[72] = Ps[wave];
  bf16x8 vb_ones;
  {
    const short one = (short)0x3F80, z = 0;
    const short e = (lr == 0) ? one : z;
    vb_ones = (bf16x8){e, e, e, e, e, e, e, e};
  }

  for (int half = 0; half < 2; ++half) {
    const int st = half ? bx : (31 - bx);   // super-tile (128 rows), heavy first
    const int q0 = st * 128;
    const int nt = st + 1;                  // KV tiles (128 wide) 0..nt-1
    const int qbase = q0 + wave * 16 + lg * 4;

    bf16x8 qf[4];
    {
      const size_t qoff = (size_t)(q0 + wave * 16 + lr) * LDQKV;
#pragma unroll
      for (int ks = 0; ks < 4; ++ks)
        qf[ks] = *(const bf16x8*)(Qp + qoff + ks * 32 + lg * 8);
    }
    f32x4 acc[8];
#pragma unroll
    for (int j = 0; j < 8; ++j) acc[j] = (f32x4){0.f, 0.f, 0.f, 0.f};
    f32x4 acc_s = (f32x4){0.f, 0.f, 0.f, 0.f};
    float mrow[4] = {-3e38f, -3e38f, -3e38f, -3e38f};
    f32x4 sc[8];
    float g8[8];

    __builtin_amdgcn_s_barrier();        // protect buf0 from previous half's reads
    STAGE_KV(0, 0);

    int kt = 0;
    for (; kt < nt - 1; ++kt) {
      STAGE_KV(kt + 1, (kt + 1) & 1);
      asm volatile("s_waitcnt vmcnt(8)" ::: "memory");
      __builtin_amdgcn_s_barrier();
#pragma unroll
      for (int cf = 0; cf < 8; ++cf) g8[cf] = gate[kt * 128 + cf * 16 + lr];
      qkt_one(Ks[kt & 1], qf, sc, lr, lg);
      softmax_pv<false>(sc, Vs[kt & 1], PsW, g8, kt * 128, qbase, acc, acc_s, mrow, lr, lg, vb_ones);
      __builtin_amdgcn_s_barrier();
    }
    // diagonal tile (kv0 == q0)
    {
      asm volatile("s_waitcnt vmcnt(0)" ::: "memory");
      __builtin_amdgcn_s_barrier();
#pragma unroll
      for (int cf = 0; cf < 8; ++cf) g8[cf] = gate[kt * 128 + cf * 16 + lr];
      qkt_one(Ks[kt & 1], qf, sc, lr, lg);
      softmax_pv<true>(sc, Vs[kt & 1], PsW, g8, kt * 128, qbase, acc, acc_s, mrow, lr, lg, vb_ones);
    }

    float inv[4];
#pragma unroll
    for (int r = 0; r < 4; ++r)
      inv[r] = 1.0f / __shfl(acc_s[r], lane & 48);
#pragma unroll
    for (int j = 0; j < 8; ++j)
#pragma unroll
      for (int r = 0; r < 4; ++r)
        Oattn[(size_t)(qbase + r) * DMODEL + h * HD + j * 16 + lr] = f2bf(acc[j][r] * inv[r]);
  }
}

// ---------------- launch ----------------

extern "C" void kernel_launch(void* const* d_in, const int* in_sizes, int n_in,
                              void* d_out, int out_size, void* d_ws, size_t ws_size,
                              hipStream_t stream) {
  (void)in_sizes; (void)n_in; (void)out_size; (void)ws_size;
  const float* hid  = (const float*)d_in[0];
  // d_in[1] = attention_mask (pure causal; recomputed inline, never read)
  const float* cosp = (const float*)d_in[2];
  const float* sinp = (const float*)d_in[3];
  const float* gate = (const float*)d_in[4];
  const float* Wq   = (const float*)d_in[5];
  const float* Wk   = (const float*)d_in[6];
  const float* Wv   = (const float*)d_in[7];
  const float* Wo   = (const float*)d_in[8];
  float* out = (float*)d_out;
  char* ws = (char*)d_ws;
  unsigned short* Xb   = (unsigned short*)(ws);                       // 16 MB  [4096][2048] bf16
  unsigned short* Wt   = (unsigned short*)(ws + (size_t)16777216);    // 12 MB  [3072][2048] bf16 (Wq|Wk|Wv)^T
  unsigned short* Wot  = (unsigned short*)(ws + (size_t)29360128);    //  8 MB  [2048][2048] bf16 Wo^T
  unsigned short* QKV  = (unsigned short*)(ws + (size_t)37748736);    // 24 MB  [4096][3072] bf16 (roped)
  unsigned short* Oatt = (unsigned short*)(ws + (size_t)62914560);    // 16 MB  [4096][2048] bf16
  unsigned short* Vt   = (unsigned short*)(ws + (size_t)79691776);    //  4 MB  [4][128][4096] bf16

  k_prep<<<10752, 256, 0, stream>>>(hid, Xb, Wq, Wk, Wv, Wo, Wt, Wot);
  k_gemm_bt<1><<<dim3(32, 24), 256, 0, stream>>>(Xb, Wt, QKV, 4096, 3072, 2048, cosp, sinp);
  k_vt<<<512, 256, 0, stream>>>(QKV, Vt);
  k_attn<<<dim3(16, 16), 512, 0, stream>>>(QKV, Vt, gate, Oatt);
  k_gemm_bt<2><<<dim3(32, 16), 256, 0, stream>>>(Oatt, Wot, out, 4096, 2048, 2048, nullptr, nullptr);
}